// Round 9
// baseline (248.413 us; speedup 1.0000x reference)
//
#include <hip/hip_runtime.h>
#include <hip/hip_bf16.h>
#include <math.h>

#define NSTEP 100
#define BATCH 16384
#define MB 16            // samples per block == MFMA dim 16
#define NBLK (BATCH/MB)  // 1024 blocks x 4 waves
#define NT 256

#define C_ALPHA 0.05f
#define C_SIGMA 0.2f
#define C_THETA 0.3f
#define C_DT    0.01f
#define C_LOWER 1e-6f
#define C_PEN   100.0f
#define LOG2E   1.4426950408889634f
#define TSCALE  (2.0f * LOG2E)      // tanh(z) = 1 - 2/(exp2(TSCALE*z)+1) (init/p-net only)
#define CRT ( 0.015f * C_DT * LOG2E)
#define CRW ( 0.1f * LOG2E)
#define CPT (-0.095f * C_DT * LOG2E)
#define CPW (-0.3f * LOG2E)

// PWL tanh table coordinate: u = TSC*z + TOFF, 1024 segments over z in [-8, 8]
#define TSC   64.0f
#define TOFF  512.0f
#define TMAX  1023.999f
#define AXD   (1.0f + C_ALPHA * C_DT)
#define SIGTHDT (C_SIGMA * C_THETA * C_DT)

// Cross-wave LDS sync WITHOUT the vmcnt(0) drain __syncthreads() implies.
#define WG_BARRIER() asm volatile("s_waitcnt lgkmcnt(0)\n\ts_barrier" ::: "memory")

typedef __attribute__((ext_vector_type(8))) short bf16x8;
typedef __attribute__((ext_vector_type(4))) float f32x4;
typedef __attribute__((ext_vector_type(4), aligned(4))) float f32x4a;

__device__ __forceinline__ float tanh_pre(float zs) {  // init/p-net only (trans)
    float e = __builtin_amdgcn_exp2f(zs);
    return 1.0f - 2.0f * __builtin_amdgcn_rcpf(e + 1.0f);
}
__device__ __forceinline__ unsigned f2bf_u(float f) {  // RNE
    unsigned u = __float_as_uint(f);
    return (u + 0x7FFFu + ((u >> 16) & 1u)) >> 16;
}
__device__ __forceinline__ unsigned pack_bf16(float a, float b) {
    union { __hip_bfloat162 h; unsigned u; } cv;
    cv.h = __float22bfloat162_rn(make_float2(a, b));   // v_cvt_pk_bf16_f32
    return cv.u;
}
// sum across each 16-lane row via DPP row_ror butterfly (epilogue loss only)
__device__ __forceinline__ float dpp_row_sum16(float v) {
    int t;
    t = __builtin_amdgcn_update_dpp(0, __float_as_int(v), 0x128, 0xF, 0xF, true);
    v += __int_as_float(t);
    t = __builtin_amdgcn_update_dpp(0, __float_as_int(v), 0x124, 0xF, 0xF, true);
    v += __int_as_float(t);
    t = __builtin_amdgcn_update_dpp(0, __float_as_int(v), 0x122, 0xF, 0xF, true);
    v += __int_as_float(t);
    t = __builtin_amdgcn_update_dpp(0, __float_as_int(v), 0x121, 0xF, 0xF, true);
    v += __int_as_float(t);
    return v;
}

__global__ __launch_bounds__(NT, 3) void fused_kernel(
        const float* __restrict__ dw, const float* __restrict__ X0,
        const float* __restrict__ R0,
        const float* __restrict__ pW1, const float* __restrict__ pb1,
        const float* __restrict__ pW2, const float* __restrict__ pb2,
        const float* __restrict__ pW3, const float* __restrict__ pb3,
        const float* __restrict__ qW1, const float* __restrict__ qb1,
        const float* __restrict__ qW2, const float* __restrict__ qb2,
        const float* __restrict__ qW3, const float* __restrict__ qb3,
        float* __restrict__ ws, float* __restrict__ out) {
    __shared__ __align__(16) unsigned short sW2T[64 * 72];  // bf16 W2^T [n][k] * TSC
    __shared__ __align__(16) float sdw[MB * NSTEP];
    __shared__ __align__(16) float2 sTab[1024];             // PWL tanh: {t, dt}
    __shared__ __align__(16) uint2 sA2[2][2][64][2];  // [parity][kstep][lane][half]

    const int tid = threadIdx.x;
    const int lane = tid & 63;
    const int wv = tid >> 6;               // wave role: k-chunk owner (L1 only)
    const int ks_own = wv >> 1;            // which kstep fragment this wave feeds
    const int half = wv & 1;               // which 8-byte half of that fragment
    const int b0 = blockIdx.x * MB;
    const int l15 = lane & 15, quad = lane >> 4;

    // ---- stage dw (coalesced float4), W2^T (bf16 * TSC), tanh PWL table ----
    {
        const float4* g = (const float4*)(dw + (size_t)b0 * NSTEP);
        float4* s = (float4*)sdw;
        for (int u = tid; u < MB * NSTEP / 4; u += NT) s[u] = g[u];
    }
    for (int u4 = tid; u4 < 1024; u4 += NT) {
        float4 w = ((const float4*)qW2)[u4];
        int base = u4 * 4;
        int k = base >> 6, n = base & 63;      // qW2[k*64+n] = W2[k][n]
        sW2T[(n + 0) * 72 + k] = (unsigned short)f2bf_u(w.x * TSC);
        sW2T[(n + 1) * 72 + k] = (unsigned short)f2bf_u(w.y * TSC);
        sW2T[(n + 2) * 72 + k] = (unsigned short)f2bf_u(w.z * TSC);
        sW2T[(n + 3) * 72 + k] = (unsigned short)f2bf_u(w.w * TSC);
    }
    for (int u = tid; u < 1024; u += NT) {     // build PWL table (one-time trans)
        float z0 = (float)u * (1.0f / TSC) - 8.0f;
        float t0 = tanh_pre(TSCALE * z0);
        float t1 = tanh_pre(TSCALE * (z0 + 1.0f / TSC));
        sTab[u] = make_float2(t0, t1 - t0);
    }
    __syncthreads();

    // PWL tanh eval: u is already the table coordinate (weights pre-scaled)
    auto tab = [&](float u) -> float {
        float uc = __builtin_amdgcn_fmed3f(u, 0.0f, TMAX);
        int idx = (int)uc;                     // trunc == floor (uc >= 0)
        float f = uc - (float)idx;
        float2 e = sTab[idx];
        return fmaf(f, e.y, e.x);
    };

    // resident W2^T fragments: ALL 4 n-tiles x 2 k-steps (every wave, full N)
    bf16x8 Bw[4][2];
    #pragma unroll
    for (int nt = 0; nt < 4; nt++) {
        const unsigned short* rp = &sW2T[(nt * 16 + l15) * 72 + quad * 8];
        Bw[nt][0] = *(const bf16x8*)rp;
        Bw[nt][1] = *(const bf16x8*)(rp + 32);
    }
    // layer-1 consts (pre-scaled by TSC, +TOFF in bias): this wave's 4 k's
    float tco[4], w1xs[4], w1rs[4], b1s[4];
    {
        const int kb = ks_own * 32 + quad * 8 + half * 4;
        #pragma unroll
        for (int j = 0; j < 4; j++) {
            tco[j]  = qW1[kb + j] * (2.0f * C_DT * TSC);
            w1xs[j] = qW1[64 + kb + j] * TSC;
            w1rs[j] = qW1[128 + kb + j] * TSC;
            b1s[j]  = qb1[kb + j] * TSC + TOFF;
        }
    }
    // full-N output consts: acc[nt][r] = table-coord of h2pre[n = nt*16+quad*4+r][sample l15]
    f32x4 b2a[4];
    float w3c[4][4];
    #pragma unroll
    for (int nt = 0; nt < 4; nt++) {
        #pragma unroll
        for (int r = 0; r < 4; r++) {
            b2a[nt][r] = qb2[nt * 16 + quad * 4 + r] * TSC + TOFF;
            w3c[nt][r] = qW3[nt * 16 + quad * 4 + r];
        }
    }
    const float b3 = qb3[0];
    const float X0v = X0[0], R0s = R0[0];

    // ---- loop-invariant LDS pointers (parity-specialized) ----
    uint2*       wA0 = &sA2[0][ks_own][lane][half];
    uint2*       wA1 = &sA2[1][ks_own][lane][half];
    const uint2* rA0 = &sA2[0][0][lane][0];        // kstep0 frag; kstep1 at +128 uint2
    const uint2* rA1 = &sA2[1][0][lane][0];

    // ---- p-net: p0, dp0 (one-time; trans ok) ----
    float p0, dp0;
    {
        float pre = fmaf(pW1[64 + lane], X0v, fmaf(pW1[128 + lane], R0s, pb1[lane]));
        float h1 = tanh_pre(TSCALE * pre);
        float d1 = (1.0f - h1 * h1) * pW1[64 + lane];
        float a0 = pb2[lane], a1 = 0.f, a2 = 0.f, a3 = 0.f;
        float e0 = 0.f, e1 = 0.f, e2 = 0.f, e3 = 0.f;
        for (int i2 = 0; i2 < 64; i2 += 4) {
            float w0 = pW2[(i2 + 0) * 64 + lane];
            float w1 = pW2[(i2 + 1) * 64 + lane];
            float w2 = pW2[(i2 + 2) * 64 + lane];
            float w3 = pW2[(i2 + 3) * 64 + lane];
            a0 = fmaf(__shfl(h1, i2 + 0), w0, a0); e0 = fmaf(__shfl(d1, i2 + 0), w0, e0);
            a1 = fmaf(__shfl(h1, i2 + 1), w1, a1); e1 = fmaf(__shfl(d1, i2 + 1), w1, e1);
            a2 = fmaf(__shfl(h1, i2 + 2), w2, a2); e2 = fmaf(__shfl(d1, i2 + 2), w2, e2);
            a3 = fmaf(__shfl(h1, i2 + 3), w3, a3); e3 = fmaf(__shfl(d1, i2 + 3), w3, e3);
        }
        float pre2 = (a0 + a1) + (a2 + a3);
        float dpre2 = (e0 + e1) + (e2 + e3);
        float h2 = tanh_pre(TSCALE * pre2);
        float d2 = (1.0f - h2 * h2) * dpre2;
        float c1 = h2 * pW3[lane], c2 = d2 * pW3[lane];
        #pragma unroll
        for (int o = 1; o < 64; o <<= 1) {
            c1 += __shfl_xor(c1, o);
            c2 += __shfl_xor(c2, o);
        }
        p0 = c1 + pb3[0]; dp0 = c2;
    }
    const float mdp0 = -dp0;

    // ---- cooperative L1 (k-split, ONE barrier) + redundant full-N output ----
    auto qnet = [&](float fi, float xv, float rv, uint2* wA, const uint2* rA) -> float {
        union { uint2 u2; unsigned u[2]; } Aloc;
        {
            float z0 = fmaf(w1xs[0], xv, fmaf(w1rs[0], rv, fmaf(tco[0], fi, b1s[0])));
            float z1 = fmaf(w1xs[1], xv, fmaf(w1rs[1], rv, fmaf(tco[1], fi, b1s[1])));
            float z2 = fmaf(w1xs[2], xv, fmaf(w1rs[2], rv, fmaf(tco[2], fi, b1s[2])));
            float z3 = fmaf(w1xs[3], xv, fmaf(w1rs[3], rv, fmaf(tco[3], fi, b1s[3])));
            Aloc.u[0] = pack_bf16(tab(z0), tab(z1));
            Aloc.u[1] = pack_bf16(tab(z2), tab(z3));
        }
        *wA = Aloc.u2;
        WG_BARRIER();                          // ONLY barrier per step
        bf16x8 A0 = *(const bf16x8*)rA;        // kstep0 frag (b128, conflict-free)
        bf16x8 A1 = *(const bf16x8*)(rA + 128);// kstep1 frag
        // every wave: full N=64 output + in-register reduce -> pi on all lanes
        float ps0 = 0.f, ps1 = 0.f, ps2 = 0.f, ps3 = 0.f;
        #pragma unroll
        for (int nt = 0; nt < 4; nt++) {
            f32x4 a = b2a[nt];
            a = __builtin_amdgcn_mfma_f32_16x16x32_bf16(Bw[nt][0], A0, a, 0, 0, 0);
            a = __builtin_amdgcn_mfma_f32_16x16x32_bf16(Bw[nt][1], A1, a, 0, 0, 0);
            ps0 = fmaf(tab(a[0]), w3c[nt][0], ps0);
            ps1 = fmaf(tab(a[1]), w3c[nt][1], ps1);
            ps2 = fmaf(tab(a[2]), w3c[nt][2], ps2);
            ps3 = fmaf(tab(a[3]), w3c[nt][3], ps3);
        }
        float ps = (ps0 + ps1) + (ps2 + ps3);  // this quad's 16 n-terms
        ps += __shfl_xor(ps, 16);              // sum quads: all 64 n-terms
        ps += __shfl_xor(ps, 32);
        return ps + b3;
    };

    // ---- t=0 row + initial pi (parity 0) ----
    float x = X0v, minx = X0v;
    float pi = qnet(0.0f, X0v, R0s, wA0, rA0);
    float* op = out + (size_t)(b0 + l15) * 5;      // running row pointer (wv3 use)
    if (wv == 3) {
        if (quad == 0) {
            f32x4a o = {X0v, R0s, pi, -p0};
            *(f32x4a*)op = o;
        } else if (quad == 1) {
            op[4] = mdp0;
        }
    }

    // R/pm/sp precomputed one iteration EARLY (exp2 off the x->z chain)
    const float* sdwp = &sdw[l15 * NSTEP];
    float dwc = sdwp[0];
    float Rn  = R0s * __builtin_amdgcn_exp2f(fmaf(CRW, dwc, CRT));
    float pmn = p0  * __builtin_amdgcn_exp2f(fmaf(CPW, dwc, CPT));
    float spn = fmaf(dwc, C_SIGMA, SIGTHDT);
    sdwp += 1;
    float fc = 1.0f;

    auto STEP = [&](uint2* wA, const uint2* rA) {
        float R = Rn, pm = pmn, sp = spn;
        float d2 = *sdwp++;                        // dw for NEXT step
        Rn  *= __builtin_amdgcn_exp2f(fmaf(CRW, d2, CRT));
        pmn *= __builtin_amdgcn_exp2f(fmaf(CPW, d2, CPT));
        spn  = fmaf(d2, C_SIGMA, SIGTHDT);
        x = fmaf(x, AXD, pi * sp);
        minx = fminf(minx, x);
        float pin = qnet(fc, x, R, wA, rA);
        if (wv == 3) {
            op += (size_t)BATCH * 5;
            if (quad == 0) {
                f32x4a o = {x, R, pin, -pm};
                *(f32x4a*)op = o;
            } else if (quad == 1) {
                op[4] = mdp0;
            }
        }
        pi = pin;
        fc += 1.0f;
    };

    // 99 pi-updating steps: parities 1,0 repeated, 49 pairs + 1 tail (parity 1)
    #pragma unroll 1
    for (int it = 0; it < 49; ++it) {
        STEP(wA1, rA1);
        STEP(wA0, rA0);
    }
    STEP(wA1, rA1);

    // ---- final step (pi not updated) + losses ----
    {
        x = fmaf(x, AXD, pi * spn);
        minx = fminf(minx, x);
        float Rf = Rn, pf = pmn;
        if (wv == 3) {
            op += (size_t)BATCH * 5;
            if (quad == 0) {
                f32x4a o = {x, Rf, pi, -pf};
                *(f32x4a*)op = o;
            } else if (quad == 1) {
                op[4] = mdp0;
            }
        }
        if (wv == 0) {
            float xc = fmaxf(x, C_LOWER);
            float ux = Rf * rsqrtf(xc);           // R * xc^(gamma-1), gamma=0.5
            float uval = 2.0f * Rf * sqrtf(xc);   // R * xc^gamma / gamma
            float d = fmaxf(C_LOWER - minx, 0.0f);
            float pen = C_PEN * d * d;
            float t1 = pf + ux;
            float v1 = dpp_row_sum16(t1 * t1 + pen);
            float v2 = dpp_row_sum16(-uval + pen);
            if (lane == 0) {
                atomicAdd(&ws[3], v1);
                atomicAdd(&ws[4], v2);
                __threadfence();
                int old = atomicAdd((int*)(ws + 5), 1);
                if (old == NBLK - 1) {   // last block finalizes losses
                    float lp = atomicAdd(&ws[3], 0.0f) * (1.0f / (float)BATCH);
                    float lq = atomicAdd(&ws[4], 0.0f) * (1.0f / (float)BATCH);
                    out[(size_t)(NSTEP + 1) * BATCH * 5] = lp;
                    out[(size_t)(NSTEP + 1) * BATCH * 5 + 1] = lp + lq;
                }
            }
        }
    }
}

extern "C" void kernel_launch(void* const* d_in, const int* in_sizes, int n_in,
                              void* d_out, int out_size, void* d_ws, size_t ws_size,
                              hipStream_t stream) {
    const float* dw  = (const float*)d_in[0];
    const float* X0  = (const float*)d_in[1];
    const float* R0  = (const float*)d_in[2];
    const float* pW1 = (const float*)d_in[3];
    const float* pb1 = (const float*)d_in[4];
    const float* pW2 = (const float*)d_in[5];
    const float* pb2 = (const float*)d_in[6];
    const float* pW3 = (const float*)d_in[7];
    const float* pb3 = (const float*)d_in[8];
    const float* qW1 = (const float*)d_in[9];
    const float* qb1 = (const float*)d_in[10];
    const float* qW2 = (const float*)d_in[11];
    const float* qb2 = (const float*)d_in[12];
    const float* qW3 = (const float*)d_in[13];
    const float* qb3 = (const float*)d_in[14];
    float* out = (float*)d_out;
    float* ws  = (float*)d_ws;

    hipMemsetAsync(d_ws, 0, 64, stream);   // zero loss accumulators + block counter
    fused_kernel<<<NBLK, NT, 0, stream>>>(dw, X0, R0, pW1, pb1, pW2, pb2, pW3, pb3,
                                          qW1, qb1, qW2, qb2, qW3, qb3, ws, out);
}

// Round 11
// 194.439 us; speedup vs baseline: 1.2776x; 1.2776x over previous
//
#include <hip/hip_runtime.h>
#include <hip/hip_bf16.h>
#include <math.h>

#define NSTEP 100
#define BATCH 16384
#define MB 16            // samples per block == MFMA dim 16
#define NBLK (BATCH/MB)  // 1024 blocks x 4 waves
#define NT 256

#define C_ALPHA 0.05f
#define C_SIGMA 0.2f
#define C_THETA 0.3f
#define C_DT    0.01f
#define C_LOWER 1e-6f
#define C_PEN   100.0f
#define LOG2E   1.4426950408889634f
#define TSCALE  (2.0f * LOG2E)      // tanh(z) = 1 - 2/(exp2(TSCALE*z)+1) (init/p-net only)
#define CRT ( 0.015f * C_DT * LOG2E)
#define CRW ( 0.1f * LOG2E)
#define CPT (-0.095f * C_DT * LOG2E)
#define CPW (-0.3f * LOG2E)

// PWL tanh table coordinate: u = TSC*z + TOFF, 1024 segments over z in [-8, 8]
#define TSC   64.0f
#define TOFF  512.0f
#define TMAX  1023.999f
#define AXD   (1.0f + C_ALPHA * C_DT)
#define SIGTHDT (C_SIGMA * C_THETA * C_DT)

// Cross-wave LDS sync WITHOUT the vmcnt(0) drain __syncthreads() implies.
#define WG_BARRIER() asm volatile("s_waitcnt lgkmcnt(0)\n\ts_barrier" ::: "memory")

typedef __attribute__((ext_vector_type(8))) short bf16x8;
typedef __attribute__((ext_vector_type(4))) float f32x4;
typedef __attribute__((ext_vector_type(4), aligned(4))) float f32x4a;

__device__ __forceinline__ float tanh_pre(float zs) {  // init/p-net only (trans)
    float e = __builtin_amdgcn_exp2f(zs);
    return 1.0f - 2.0f * __builtin_amdgcn_rcpf(e + 1.0f);
}
__device__ __forceinline__ unsigned f2bf_u(float f) {  // RNE
    unsigned u = __float_as_uint(f);
    return (u + 0x7FFFu + ((u >> 16) & 1u)) >> 16;
}
__device__ __forceinline__ unsigned pack_bf16(float a, float b) {
    union { __hip_bfloat162 h; unsigned u; } cv;
    cv.h = __float22bfloat162_rn(make_float2(a, b));   // v_cvt_pk_bf16_f32
    return cv.u;
}
// sum across each 16-lane row via DPP row_ror butterfly (epilogue loss only)
__device__ __forceinline__ float dpp_row_sum16(float v) {
    int t;
    t = __builtin_amdgcn_update_dpp(0, __float_as_int(v), 0x128, 0xF, 0xF, true);
    v += __int_as_float(t);
    t = __builtin_amdgcn_update_dpp(0, __float_as_int(v), 0x124, 0xF, 0xF, true);
    v += __int_as_float(t);
    t = __builtin_amdgcn_update_dpp(0, __float_as_int(v), 0x122, 0xF, 0xF, true);
    v += __int_as_float(t);
    t = __builtin_amdgcn_update_dpp(0, __float_as_int(v), 0x121, 0xF, 0xF, true);
    v += __int_as_float(t);
    return v;
}

__global__ __launch_bounds__(NT, 4) void fused_kernel(
        const float* __restrict__ dw, const float* __restrict__ X0,
        const float* __restrict__ R0,
        const float* __restrict__ pW1, const float* __restrict__ pb1,
        const float* __restrict__ pW2, const float* __restrict__ pb2,
        const float* __restrict__ pW3, const float* __restrict__ pb3,
        const float* __restrict__ qW1, const float* __restrict__ qb1,
        const float* __restrict__ qW2, const float* __restrict__ qb2,
        const float* __restrict__ qW3, const float* __restrict__ qb3,
        float* __restrict__ ws, float* __restrict__ out) {
    __shared__ __align__(16) unsigned short sW2T[64 * 72];  // bf16 W2^T [n][k] * TSC
    __shared__ __align__(16) float sdw[MB * NSTEP];
    __shared__ __align__(16) float2 sTab[1024];             // PWL tanh: {t, dt}
    __shared__ __align__(16) uint2 sA2[2][2][64][2];  // [parity][kstep][lane][half]
    __shared__ __align__(16) float sPb[2][2][16][2];  // [parity][wavepair][sample][lo/hi]

    const int tid = threadIdx.x;
    const int lane = tid & 63;
    const int wv = tid >> 6;               // wave role: n-tile owner + k-chunk owner
    const int ks_own = wv >> 1;            // which kstep fragment this wave feeds
    const int half = wv & 1;               // which 8-byte half of that fragment
    const int b0 = blockIdx.x * MB;
    const int l15 = lane & 15, quad = lane >> 4;

    // ---- stage dw (coalesced float4), W2^T (bf16 * TSC), tanh PWL table ----
    {
        const float4* g = (const float4*)(dw + (size_t)b0 * NSTEP);
        float4* s = (float4*)sdw;
        for (int u = tid; u < MB * NSTEP / 4; u += NT) s[u] = g[u];
    }
    for (int u4 = tid; u4 < 1024; u4 += NT) {
        float4 w = ((const float4*)qW2)[u4];
        int base = u4 * 4;
        int k = base >> 6, n = base & 63;      // qW2[k*64+n] = W2[k][n]
        sW2T[(n + 0) * 72 + k] = (unsigned short)f2bf_u(w.x * TSC);
        sW2T[(n + 1) * 72 + k] = (unsigned short)f2bf_u(w.y * TSC);
        sW2T[(n + 2) * 72 + k] = (unsigned short)f2bf_u(w.z * TSC);
        sW2T[(n + 3) * 72 + k] = (unsigned short)f2bf_u(w.w * TSC);
    }
    for (int u = tid; u < 1024; u += NT) {     // build PWL table (one-time trans)
        float z0 = (float)u * (1.0f / TSC) - 8.0f;
        float t0 = tanh_pre(TSCALE * z0);
        float t1 = tanh_pre(TSCALE * (z0 + 1.0f / TSC));
        sTab[u] = make_float2(t0, t1 - t0);
    }
    __syncthreads();

    // split-tab: address-prep (no load) — used for BATCHED gather phases
    auto tab_prep = [&](float u, float& f) -> const float2* {
        float uc = __builtin_amdgcn_fmed3f(u, 0.0f, TMAX);
        int idx = (int)uc;                     // trunc == floor (uc >= 0)
        f = uc - (float)idx;
        return &sTab[idx];
    };

    // resident W2^T fragments: this wave's n-tile (nt = wv), 2 k-steps.
    bf16x8 Bw0, Bw1;
    {
        const unsigned short* rp = &sW2T[(wv * 16 + l15) * 72 + quad * 8];
        Bw0 = *(const bf16x8*)rp;
        Bw1 = *(const bf16x8*)(rp + 32);
    }
    // layer-1 consts (pre-scaled by TSC, +TOFF in bias): this wave's 4 k's
    float tco[4], w1xs[4], w1rs[4], b1s[4];
    {
        const int kb = ks_own * 32 + quad * 8 + half * 4;
        #pragma unroll
        for (int j = 0; j < 4; j++) {
            tco[j]  = qW1[kb + j] * (2.0f * C_DT * TSC);
            w1xs[j] = qW1[64 + kb + j] * TSC;
            w1rs[j] = qW1[128 + kb + j] * TSC;
            b1s[j]  = qb1[kb + j] * TSC + TOFF;
        }
    }
    // swapped-output consts: acc[r] = table-coord of h2pre[n = wv*16+quad*4+r][sample l15]
    f32x4 b2w;
    float w3w[4];
    #pragma unroll
    for (int r = 0; r < 4; r++) {
        b2w[r] = qb2[wv * 16 + quad * 4 + r] * TSC + TOFF;
        w3w[r] = qW3[wv * 16 + quad * 4 + r];
    }
    const float b3 = qb3[0];
    const float X0v = X0[0], R0s = R0[0];

    // ---- loop-invariant LDS pointers (parity-specialized, computed ONCE) ----
    uint2*       wA0 = &sA2[0][ks_own][lane][half];
    uint2*       wA1 = &sA2[1][ks_own][lane][half];
    const uint2* rA0 = &sA2[0][0][lane][0];        // A0 frag; A1 at +128 uint2
    const uint2* rA1 = &sA2[1][0][lane][0];
    float*        wP0 = &sPb[0][wv >> 1][l15][wv & 1];
    float*        wP1 = &sPb[1][wv >> 1][l15][wv & 1];
    const float2* rP0 = (const float2*)&sPb[0][0][l15][0];  // +16 float2 = hi pair
    const float2* rP1 = (const float2*)&sPb[1][0][l15][0];

    // ---- p-net: p0, dp0 (one-time; trans ok) ----
    float p0, dp0;
    {
        float pre = fmaf(pW1[64 + lane], X0v, fmaf(pW1[128 + lane], R0s, pb1[lane]));
        float h1 = tanh_pre(TSCALE * pre);
        float d1 = (1.0f - h1 * h1) * pW1[64 + lane];
        float a0 = pb2[lane], a1 = 0.f, a2 = 0.f, a3 = 0.f;
        float e0 = 0.f, e1 = 0.f, e2 = 0.f, e3 = 0.f;
        for (int i2 = 0; i2 < 64; i2 += 4) {
            float w0 = pW2[(i2 + 0) * 64 + lane];
            float w1 = pW2[(i2 + 1) * 64 + lane];
            float w2 = pW2[(i2 + 2) * 64 + lane];
            float w3 = pW2[(i2 + 3) * 64 + lane];
            a0 = fmaf(__shfl(h1, i2 + 0), w0, a0); e0 = fmaf(__shfl(d1, i2 + 0), w0, e0);
            a1 = fmaf(__shfl(h1, i2 + 1), w1, a1); e1 = fmaf(__shfl(d1, i2 + 1), w1, e1);
            a2 = fmaf(__shfl(h1, i2 + 2), w2, a2); e2 = fmaf(__shfl(d1, i2 + 2), w2, e2);
            a3 = fmaf(__shfl(h1, i2 + 3), w3, a3); e3 = fmaf(__shfl(d1, i2 + 3), w3, e3);
        }
        float pre2 = (a0 + a1) + (a2 + a3);
        float dpre2 = (e0 + e1) + (e2 + e3);
        float h2 = tanh_pre(TSCALE * pre2);
        float d2 = (1.0f - h2 * h2) * dpre2;
        float c1 = h2 * pW3[lane], c2 = d2 * pW3[lane];
        #pragma unroll
        for (int o = 1; o < 64; o <<= 1) {
            c1 += __shfl_xor(c1, o);
            c2 += __shfl_xor(c2, o);
        }
        p0 = c1 + pb3[0]; dp0 = c2;
    }
    const float mdp0 = -dp0;

    // ---- cooperative q-net (R8 structure + BATCHED table gathers) ----
    auto qnet = [&](float fi, float xv, float rv, uint2* wA, const uint2* rA,
                    float* wP, const float2* rP) -> float {
        union { uint2 u2; unsigned u[2]; } Aloc;
        {
            // all 4 z's (independent fma chains)
            float z0 = fmaf(w1xs[0], xv, fmaf(w1rs[0], rv, fmaf(tco[0], fi, b1s[0])));
            float z1 = fmaf(w1xs[1], xv, fmaf(w1rs[1], rv, fmaf(tco[1], fi, b1s[1])));
            float z2 = fmaf(w1xs[2], xv, fmaf(w1rs[2], rv, fmaf(tco[2], fi, b1s[2])));
            float z3 = fmaf(w1xs[3], xv, fmaf(w1rs[3], rv, fmaf(tco[3], fi, b1s[3])));
            // batched gather: 4 addresses, then 4 back-to-back ds_read_b64,
            // then 4 consumes -> ONE latency exposure instead of four
            float f0, f1, f2, f3;
            const float2* q0 = tab_prep(z0, f0);
            const float2* q1 = tab_prep(z1, f1);
            const float2* q2 = tab_prep(z2, f2);
            const float2* q3 = tab_prep(z3, f3);
            float2 e0 = *q0, e1 = *q1, e2 = *q2, e3 = *q3;
            float h0 = fmaf(f0, e0.y, e0.x);
            float h1 = fmaf(f1, e1.y, e1.x);
            float h2 = fmaf(f2, e2.y, e2.x);
            float h3 = fmaf(f3, e3.y, e3.x);
            Aloc.u[0] = pack_bf16(h0, h1);
            Aloc.u[1] = pack_bf16(h2, h3);
        }
        *wA = Aloc.u2;
        WG_BARRIER();                          // B1: all A half-fragments in LDS
        bf16x8 A0 = *(const bf16x8*)rA;        // kstep0 frag (b128)
        bf16x8 A1 = *(const bf16x8*)(rA + 128);// kstep1 frag
        f32x4 acc = b2w;
        acc = __builtin_amdgcn_mfma_f32_16x16x32_bf16(Bw0, A0, acc, 0, 0, 0);
        acc = __builtin_amdgcn_mfma_f32_16x16x32_bf16(Bw1, A1, acc, 0, 0, 0);
        // batched out-gathers (4 independent)
        float g0, g1, g2, g3;
        const float2* r0 = tab_prep(acc[0], g0);
        const float2* r1 = tab_prep(acc[1], g1);
        const float2* r2 = tab_prep(acc[2], g2);
        const float2* r3 = tab_prep(acc[3], g3);
        float2 d0 = *r0, d1 = *r1, d2 = *r2, d3 = *r3;
        float o0 = fmaf(g0, d0.y, d0.x);
        float o1 = fmaf(g1, d1.y, d1.x);
        float o2 = fmaf(g2, d2.y, d2.x);
        float o3 = fmaf(g3, d3.y, d3.x);
        float ps = fmaf(o0, w3w[0], fmaf(o1, w3w[1], fmaf(o2, w3w[2], o3 * w3w[3])));
        ps += __shfl_xor(ps, 16);              // full 16-n partial, replicated
        ps += __shfl_xor(ps, 32);
        if (quad == 0) *wP = ps;
        WG_BARRIER();                          // B2: partials exchanged
        float2 pa = rP[0], pb = rP[16];        // 2 x ds_read_b64 (broadcast)
        return ((pa.x + pa.y) + (pb.x + pb.y)) + b3;
    };

    // ---- t=0 row + initial pi (parity 0) ----
    float x = X0v, minx = X0v;
    float pi = qnet(0.0f, X0v, R0s, wA0, rA0, wP0, rP0);
    float* op = out + (size_t)(b0 + l15) * 5;      // running row pointer (wv3 use)
    if (wv == 3) {
        if (quad == 0) {
            f32x4a o = {X0v, R0s, pi, -p0};
            *(f32x4a*)op = o;
        } else if (quad == 1) {
            op[4] = mdp0;
        }
    }

    // R/pm/sp precomputed one iteration EARLY (exp2 off the x->z chain)
    const float* sdwp = &sdw[l15 * NSTEP];
    float dwc = sdwp[0];
    float Rn  = R0s * __builtin_amdgcn_exp2f(fmaf(CRW, dwc, CRT));
    float pmn = p0  * __builtin_amdgcn_exp2f(fmaf(CPW, dwc, CPT));
    float spn = fmaf(dwc, C_SIGMA, SIGTHDT);
    sdwp += 1;
    float fc = 1.0f;

    auto STEP = [&](uint2* wA, const uint2* rA, float* wP, const float2* rP) {
        float R = Rn, pm = pmn, sp = spn;
        float d2 = *sdwp++;                        // dw for NEXT step
        Rn  *= __builtin_amdgcn_exp2f(fmaf(CRW, d2, CRT));
        pmn *= __builtin_amdgcn_exp2f(fmaf(CPW, d2, CPT));
        spn  = fmaf(d2, C_SIGMA, SIGTHDT);
        x = fmaf(x, AXD, pi * sp);
        minx = fminf(minx, x);
        float pin = qnet(fc, x, R, wA, rA, wP, rP);
        if (wv == 3) {
            op += (size_t)BATCH * 5;
            if (quad == 0) {
                f32x4a o = {x, R, pin, -pm};
                *(f32x4a*)op = o;
            } else if (quad == 1) {
                op[4] = mdp0;
            }
        }
        pi = pin;
        fc += 1.0f;
    };

    // 99 pi-updating steps: parities 1,0 repeated, 49 pairs + 1 tail (parity 1)
    #pragma unroll 1
    for (int it = 0; it < 49; ++it) {
        STEP(wA1, rA1, wP1, rP1);
        STEP(wA0, rA0, wP0, rP0);
    }
    STEP(wA1, rA1, wP1, rP1);

    // ---- final step (pi not updated) + losses ----
    {
        x = fmaf(x, AXD, pi * spn);
        minx = fminf(minx, x);
        float Rf = Rn, pf = pmn;
        if (wv == 3) {
            op += (size_t)BATCH * 5;
            if (quad == 0) {
                f32x4a o = {x, Rf, pi, -pf};
                *(f32x4a*)op = o;
            } else if (quad == 1) {
                op[4] = mdp0;
            }
        }
        if (wv == 0) {
            float xc = fmaxf(x, C_LOWER);
            float ux = Rf * rsqrtf(xc);           // R * xc^(gamma-1), gamma=0.5
            float uval = 2.0f * Rf * sqrtf(xc);   // R * xc^gamma / gamma
            float d = fmaxf(C_LOWER - minx, 0.0f);
            float pen = C_PEN * d * d;
            float t1 = pf + ux;
            float v1 = dpp_row_sum16(t1 * t1 + pen);
            float v2 = dpp_row_sum16(-uval + pen);
            if (lane == 0) {
                atomicAdd(&ws[3], v1);
                atomicAdd(&ws[4], v2);
                __threadfence();
                int old = atomicAdd((int*)(ws + 5), 1);
                if (old == NBLK - 1) {   // last block finalizes losses
                    float lp = atomicAdd(&ws[3], 0.0f) * (1.0f / (float)BATCH);
                    float lq = atomicAdd(&ws[4], 0.0f) * (1.0f / (float)BATCH);
                    out[(size_t)(NSTEP + 1) * BATCH * 5] = lp;
                    out[(size_t)(NSTEP + 1) * BATCH * 5 + 1] = lp + lq;
                }
            }
        }
    }
}

extern "C" void kernel_launch(void* const* d_in, const int* in_sizes, int n_in,
                              void* d_out, int out_size, void* d_ws, size_t ws_size,
                              hipStream_t stream) {
    const float* dw  = (const float*)d_in[0];
    const float* X0  = (const float*)d_in[1];
    const float* R0  = (const float*)d_in[2];
    const float* pW1 = (const float*)d_in[3];
    const float* pb1 = (const float*)d_in[4];
    const float* pW2 = (const float*)d_in[5];
    const float* pb2 = (const float*)d_in[6];
    const float* pW3 = (const float*)d_in[7];
    const float* pb3 = (const float*)d_in[8];
    const float* qW1 = (const float*)d_in[9];
    const float* qb1 = (const float*)d_in[10];
    const float* qW2 = (const float*)d_in[11];
    const float* qb2 = (const float*)d_in[12];
    const float* qW3 = (const float*)d_in[13];
    const float* qb3 = (const float*)d_in[14];
    float* out = (float*)d_out;
    float* ws  = (float*)d_ws;

    hipMemsetAsync(d_ws, 0, 64, stream);   // zero loss accumulators + block counter
    fused_kernel<<<NBLK, NT, 0, stream>>>(dw, X0, R0, pW1, pb1, pW2, pb2, pW3, pb3,
                                          qW1, qb1, qW2, qb2, qW3, qb3, ws, out);
}